// Round 4
// baseline (475.624 us; speedup 1.0000x reference)
//
#include <hip/hip_runtime.h>
#include <math.h>

#define HEADS 4
#define CH 64
#define HC 256
#define NEG 0.2f

#define NB 256   // grid blocks (co-residency guaranteed: ~4KB LDS, low VGPR)
#define NT 256   // threads per block

// caps (expected: deg(N-1)~17, |S1|~18, e1~300)
#define CAP_E2 64
#define CAP_U  512
#define H0CAP  2048
#define MAXD   64

__device__ __forceinline__ float wave_sum64(float v) {
    #pragma unroll
    for (int off = 32; off; off >>= 1) v += __shfl_down(v, off, 64);
    return v;  // valid in lane 0
}

// software grid barrier: bar[0]=arrive count, bar[1]=generation (both start 0)
__device__ __forceinline__ void gbar(int* bar) {
    __syncthreads();
    __threadfence();  // flush this block's writes to device scope
    if (threadIdx.x == 0) {
        int g = __hip_atomic_load(&bar[1], __ATOMIC_ACQUIRE, __HIP_MEMORY_SCOPE_AGENT);
        int a = __hip_atomic_fetch_add(&bar[0], 1, __ATOMIC_ACQ_REL, __HIP_MEMORY_SCOPE_AGENT) + 1;
        if (a == NB) {
            __hip_atomic_store(&bar[0], 0, __ATOMIC_RELAXED, __HIP_MEMORY_SCOPE_AGENT);
            __hip_atomic_fetch_add(&bar[1], 1, __ATOMIC_RELEASE, __HIP_MEMORY_SCOPE_AGENT);
        } else {
            while (__hip_atomic_load(&bar[1], __ATOMIC_ACQUIRE, __HIP_MEMORY_SCOPE_AGENT) == g)
                __builtin_amdgcn_s_sleep(1);
        }
    }
    __syncthreads();
    __threadfence();  // invalidate caches before reading others' writes
}

__global__ __launch_bounds__(NT) void k_mega(
    const int* __restrict__ y, const int* __restrict__ ei,
    const float* __restrict__ emb,
    const float* __restrict__ W0, const float* __restrict__ as0,
    const float* __restrict__ ad0, const float* __restrict__ b0,
    const float* __restrict__ W1, const float* __restrict__ as1,
    const float* __restrict__ ad1, const float* __restrict__ b1,
    const float* __restrict__ pw1, const float* __restrict__ pb1,
    const float* __restrict__ pw2, const float* __restrict__ pb2,
    int* __restrict__ bar, int* __restrict__ cnt, int* __restrict__ pos,
    int* __restrict__ e2_src, int* __restrict__ uniq,
    int* __restrict__ e1s, int* __restrict__ e1d,
    float* __restrict__ als0, float* __restrict__ alss,
    float* __restrict__ alds, float* __restrict__ als1,
    float* __restrict__ h0, float* __restrict__ h0self,
    float* __restrict__ h1, float* __restrict__ hidden,
    float* __restrict__ out, int N, int E, int V)
{
    __shared__ float xr[HC];
    __shared__ int gidx[MAXD];
    __shared__ int nloc_s;
    __shared__ float earr[MAXD + 1][HEADS];
    __shared__ float red[HEADS];
    __shared__ float part[HEADS][CH];
    __shared__ int jself_s;

    int tid = threadIdx.x, wave = tid >> 6, lane = tid & 63;
    int gid = blockIdx.x * NT + tid;

    // ---- P1: edges into N-1; claim S1 (pos: 0=no, 1=transient, u+2=member) --
    for (int e = gid; e < E; e += NB * NT) {
        int d = ei[E + e];
        if (d == N - 1) {
            int s = ei[e];
            int j = atomicAdd(&cnt[0], 1);
            if (j < CAP_E2) e2_src[j] = s;
            if (atomicCAS(&pos[s], 0, 1) == 0) {
                int u = atomicAdd(&cnt[1], 1);
                if (u < CAP_U) { uniq[u] = s; pos[s] = u + 2; } else pos[s] = 2;
            }
        }
    }
    if (gid == 0) {  // appended self loop of node N-1
        int j = atomicAdd(&cnt[0], 1);
        if (j < CAP_E2) e2_src[j] = N - 1;
        if (atomicCAS(&pos[N - 1], 0, 1) == 0) {
            int u = atomicAdd(&cnt[1], 1);
            if (u < CAP_U) { uniq[u] = N - 1; pos[N - 1] = u + 2; } else pos[N - 1] = 2;
        }
    }
    gbar(bar);

    // ---- P2: collect edges with dst in S1; self h0 rows per S1 node --------
    int ucnt = min(cnt[1], CAP_U);
    for (int e = gid; e < E; e += NB * NT) {
        int d = ei[E + e];
        if (pos[d] >= 2) {
            int j = atomicAdd(&cnt[2], 1);
            if (j < H0CAP) { e1s[j] = ei[e]; e1d[j] = d; }
        }
    }
    for (int u = blockIdx.x; u < ucnt; u += NB) {
        int node = uniq[u];
        if (tid < CH) xr[tid] = emb[(long)y[node] * CH + tid];
        __syncthreads();
        float acc = 0.f;
        #pragma unroll
        for (int k = 0; k < CH; ++k) acc = fmaf(xr[k], W0[k * HC + tid], acc);
        h0self[(long)u * HC + tid] = acc;
        float rs = wave_sum64(acc * as0[tid]);
        if (lane == 0) alss[u * HEADS + wave] = rs;
        float rd = wave_sum64(acc * ad0[tid]);
        if (lane == 0) alds[u * HEADS + wave] = rd;
        __syncthreads();
    }
    gbar(bar);

    // ---- P3: h0 row + a_src logit per layer-0 edge --------------------------
    int ce1 = min(cnt[2], H0CAP);
    for (int i = blockIdx.x; i < ce1; i += NB) {
        int node = e1s[i];
        if (tid < CH) xr[tid] = emb[(long)y[node] * CH + tid];
        __syncthreads();
        float acc = 0.f;
        #pragma unroll
        for (int k = 0; k < CH; ++k) acc = fmaf(xr[k], W0[k * HC + tid], acc);
        h0[(long)i * HC + tid] = acc;
        float r = wave_sum64(acc * as0[tid]);
        if (lane == 0) als0[i * HEADS + wave] = r;
        __syncthreads();
    }
    gbar(bar);

    // ---- P4: per S1 node attention/aggregate/elu/norm + fused layer-1 GEMV --
    int ne = min(cnt[0], CAP_E2);
    for (int u = blockIdx.x; u < ucnt; u += NB) {
        int d = uniq[u];
        if (tid == 0) nloc_s = 0;
        __syncthreads();
        for (int i = tid; i < ce1; i += NT)
            if (e1d[i] == d) {
                int s = atomicAdd(&nloc_s, 1);
                if (s < MAXD) gidx[s] = i;
            }
        __syncthreads();
        int nloc = min(nloc_s, MAXD);
        for (int idx = tid; idx < (nloc + 1) * HEADS; idx += NT) {
            int j = idx >> 2, h = idx & 3;
            float asv = (j < nloc) ? als0[gidx[j] * HEADS + h] : alss[u * HEADS + h];
            float e = asv + alds[u * HEADS + h];
            earr[j][h] = (e >= 0.f) ? e : NEG * e;
        }
        __syncthreads();
        if (tid < HEADS) {
            float m = -1e30f;
            for (int j = 0; j <= nloc; ++j) m = fmaxf(m, earr[j][tid]);
            float den = 0.f;
            for (int j = 0; j <= nloc; ++j) { float w = expf(earr[j][tid] - m); earr[j][tid] = w; den += w; }
            float inv = 1.f / (den + 1e-16f);
            for (int j = 0; j <= nloc; ++j) earr[j][tid] *= inv;
        }
        __syncthreads();
        float acc = 0.f;
        for (int j = 0; j < nloc; ++j)
            acc = fmaf(earr[j][wave], h0[(long)gidx[j] * HC + tid], acc);
        acc = fmaf(earr[nloc][wave], h0self[(long)u * HC + tid], acc);
        float o = acc + b0[tid];
        o = (o > 0.f) ? o : expm1f(o);
        float ss = wave_sum64(o * o);
        if (lane == 0) red[wave] = ss;
        __syncthreads();
        float nrm = sqrtf(red[0] + red[1] + red[2] + red[3]);
        xr[tid] = o / fmaxf(nrm, 1e-12f);  // x1 of node d in LDS
        __syncthreads();
        // fused layer-1 rows for e2 edges sourced at this node
        for (int j = 0; j < ne; ++j) {
            if (pos[e2_src[j]] - 2 != u) continue;  // wave-uniform
            float a1 = 0.f;
            #pragma unroll 16
            for (int k = 0; k < HC; ++k) a1 = fmaf(xr[k], W1[k * HC + tid], a1);
            h1[j * HC + tid] = a1;
            float r = wave_sum64(a1 * as1[tid]);
            if (lane == 0) als1[j * HEADS + wave] = r;
        }
        __syncthreads();
    }
    gbar(bar);

    // ---- P5: attention at N-1 + ctx MLP (block 0 only) ----------------------
    if (blockIdx.x == 0) {
        if (tid == 0) {
            jself_s = 0;
            for (int j = 0; j < ne; ++j) if (e2_src[j] == N - 1) { jself_s = j; break; }
        }
        __syncthreads();
        int jself = jself_s;
        {
            float r = wave_sum64(h1[jself * HC + tid] * ad1[tid]);
            if (lane == 0) red[wave] = r;  // reuse red as al_dst
        }
        __syncthreads();
        for (int idx = tid; idx < ne * HEADS; idx += NT) {
            int j = idx >> 2, h = idx & 3;
            float e = als1[j * HEADS + h] + red[h];
            earr[j][h] = (e >= 0.f) ? e : NEG * e;
        }
        __syncthreads();
        if (tid < HEADS) {
            float m = -1e30f;
            for (int j = 0; j < ne; ++j) m = fmaxf(m, earr[j][tid]);
            float den = 0.f;
            for (int j = 0; j < ne; ++j) { float w = expf(earr[j][tid] - m); earr[j][tid] = w; den += w; }
            float inv = 1.f / (den + 1e-16f);
            for (int j = 0; j < ne; ++j) earr[j][tid] *= inv;
        }
        __syncthreads();
        float acc = 0.f;
        for (int j = 0; j < ne; ++j)
            acc = fmaf(earr[j][wave], h1[j * HC + tid], acc);
        float o = acc + b1[tid];
        o = (o > 0.f) ? o : expm1f(o);
        float ss = wave_sum64(o * o);
        __syncthreads();   // red still holds al_dst; reuse after sync
        if (lane == 0) red[wave] = ss;
        __syncthreads();
        float nrm = sqrtf(red[0] + red[1] + red[2] + red[3]);
        xr[tid] = o / fmaxf(nrm, 1e-12f);  // ctx in LDS
        __syncthreads();
        int col = tid & 63;
        float hv = 0.f;
        #pragma unroll 16
        for (int k = wave * 64; k < wave * 64 + 64; ++k)
            hv = fmaf(xr[k], pw1[k * CH + col], hv);
        part[wave][col] = hv;
        __syncthreads();
        if (tid < CH) {
            float v = part[0][tid] + part[1][tid] + part[2][tid] + part[3][tid] + pb1[tid];
            hidden[tid] = fmaxf(v, 0.f);
        }
    }
    gbar(bar);

    // ---- P6: out = hidden @ pw2 + pb2 (grid-stride) --------------------------
    if (tid < CH) xr[tid] = hidden[tid];
    __syncthreads();
    int V4 = V >> 2;
    for (int q = gid; q < V4; q += NB * NT) {
        int v0 = q * 4;
        float4 acc = *(const float4*)(pb2 + v0);
        #pragma unroll 8
        for (int k = 0; k < CH; ++k) {
            float hk = xr[k];
            float4 w = *(const float4*)(pw2 + (size_t)k * V + v0);
            acc.x = fmaf(hk, w.x, acc.x);
            acc.y = fmaf(hk, w.y, acc.y);
            acc.z = fmaf(hk, w.z, acc.z);
            acc.w = fmaf(hk, w.w, acc.w);
        }
        *(float4*)(out + v0) = acc;
    }
    for (int v = (V4 << 2) + gid; v < V; v += NB * NT) {  // tail (V%4)
        float acc = pb2[v];
        for (int k = 0; k < CH; ++k) acc = fmaf(xr[k], pw2[(size_t)k * V + v], acc);
        out[v] = acc;
    }
}

extern "C" void kernel_launch(void* const* d_in, const int* in_sizes, int n_in,
                              void* d_out, int out_size, void* d_ws, size_t ws_size,
                              hipStream_t stream) {
    const int*   y      = (const int*)d_in[0];
    const int*   ei     = (const int*)d_in[1];
    const float* emb    = (const float*)d_in[2];
    const float* W0     = (const float*)d_in[3];
    const float* a_src0 = (const float*)d_in[4];
    const float* a_dst0 = (const float*)d_in[5];
    const float* b0     = (const float*)d_in[6];
    const float* W1     = (const float*)d_in[7];
    const float* a_src1 = (const float*)d_in[8];
    const float* a_dst1 = (const float*)d_in[9];
    const float* b1     = (const float*)d_in[10];
    const float* pw1    = (const float*)d_in[11];
    const float* pb1    = (const float*)d_in[12];
    const float* pw2    = (const float*)d_in[13];
    const float* pb2    = (const float*)d_in[14];
    int N = in_sizes[0];
    int E = in_sizes[1] / 2;
    int V = in_sizes[14];
    float* out = (float*)d_out;

    char* p = (char*)d_ws;
    auto alloc = [&](size_t bytes) {
        char* r = p;
        p += (bytes + 255) & ~(size_t)255;
        return r;
    };
    // zeroed region: bar[2] @0, cnt[3] @4, pos[N] @16
    int*   ints    = (int*)alloc((size_t)(16 + N) * sizeof(int));
    int*   bar     = ints;
    int*   cnt     = ints + 4;
    int*   pos     = ints + 16;
    float* hidden  = (float*)alloc(CH * sizeof(float));
    int*   e2      = (int*)alloc(CAP_E2 * sizeof(int));
    int*   uniq    = (int*)alloc(CAP_U * sizeof(int));
    int*   e1s     = (int*)alloc(H0CAP * sizeof(int));
    int*   e1d     = (int*)alloc(H0CAP * sizeof(int));
    float* als0    = (float*)alloc((size_t)H0CAP * HEADS * sizeof(float));
    float* alss    = (float*)alloc((size_t)CAP_U * HEADS * sizeof(float));
    float* alds    = (float*)alloc((size_t)CAP_U * HEADS * sizeof(float));
    float* als1    = (float*)alloc((size_t)CAP_E2 * HEADS * sizeof(float));
    float* h0      = (float*)alloc((size_t)H0CAP * HC * sizeof(float));
    float* h0self  = (float*)alloc((size_t)CAP_U * HC * sizeof(float));
    float* h1      = (float*)alloc((size_t)CAP_E2 * HC * sizeof(float));

    hipMemsetAsync(ints, 0, (size_t)(16 + N) * sizeof(int), stream);

    k_mega<<<NB, NT, 0, stream>>>(y, ei, emb, W0, a_src0, a_dst0, b0,
                                  W1, a_src1, a_dst1, b1, pw1, pb1, pw2, pb2,
                                  bar, cnt, pos, e2, uniq, e1s, e1d,
                                  als0, alss, alds, als1, h0, h0self, h1,
                                  hidden, out, N, E, V);
}

// Round 5
// 237.619 us; speedup vs baseline: 2.0016x; 2.0016x over previous
//
#include <hip/hip_runtime.h>
#include <math.h>

#define HEADS 4
#define CH 64
#define HC 256
#define NEG 0.2f

#define NB 256   // grid blocks (co-residency guaranteed: ~4KB LDS, 48 VGPR)
#define NT 256   // threads per block

// caps (expected: deg(N-1)~17, |S1|~18, e1~300)
#define CAP_E2 64
#define CAP_U  512
#define H0CAP  2048
#define MAXD   64

__device__ __forceinline__ float wave_sum64(float v) {
    #pragma unroll
    for (int off = 32; off; off >>= 1) v += __shfl_down(v, off, 64);
    return v;  // valid in lane 0
}

// software grid barrier: bar[0]=arrive count, bar[1]=generation (both start 0).
// RELAXED spin (no per-iteration cache invalidate!) + leader-only fences.
__device__ __forceinline__ void gbar(int* bar) {
    __syncthreads();  // drains this block's stores to L2 (vmcnt(0))
    if (threadIdx.x == 0) {
        __builtin_amdgcn_fence(__ATOMIC_RELEASE, "agent");  // wb L2 once
        int g = __hip_atomic_load(&bar[1], __ATOMIC_RELAXED, __HIP_MEMORY_SCOPE_AGENT);
        int a = __hip_atomic_fetch_add(&bar[0], 1, __ATOMIC_RELAXED, __HIP_MEMORY_SCOPE_AGENT) + 1;
        if (a == NB) {
            __hip_atomic_store(&bar[0], 0, __ATOMIC_RELAXED, __HIP_MEMORY_SCOPE_AGENT);
            // release: orders the bar[0] reset before the generation bump
            __hip_atomic_store(&bar[1], g + 1, __ATOMIC_RELEASE, __HIP_MEMORY_SCOPE_AGENT);
        } else {
            while (__hip_atomic_load(&bar[1], __ATOMIC_RELAXED, __HIP_MEMORY_SCOPE_AGENT) == g)
                __builtin_amdgcn_s_sleep(8);
        }
        __builtin_amdgcn_fence(__ATOMIC_ACQUIRE, "agent");  // inv once after exit
    }
    __syncthreads();
}

__global__ __launch_bounds__(NT) void k_mega(
    const int* __restrict__ y, const int* __restrict__ ei,
    const float* __restrict__ emb,
    const float* __restrict__ W0, const float* __restrict__ as0,
    const float* __restrict__ ad0, const float* __restrict__ b0,
    const float* __restrict__ W1, const float* __restrict__ as1,
    const float* __restrict__ ad1, const float* __restrict__ b1,
    const float* __restrict__ pw1, const float* __restrict__ pb1,
    const float* __restrict__ pw2, const float* __restrict__ pb2,
    int* __restrict__ bar, int* __restrict__ cnt, int* __restrict__ pos,
    int* __restrict__ e2_src, int* __restrict__ uniq,
    int* __restrict__ e1s, int* __restrict__ e1d,
    float* __restrict__ als0, float* __restrict__ alss,
    float* __restrict__ alds, float* __restrict__ als1,
    float* __restrict__ h0, float* __restrict__ h0self,
    float* __restrict__ h1, float* __restrict__ hidden,
    float* __restrict__ out, int N, int E, int V)
{
    __shared__ float xr[HC];
    __shared__ int gidx[MAXD];
    __shared__ int nloc_s;
    __shared__ float earr[MAXD + 1][HEADS];
    __shared__ float red[HEADS];
    __shared__ float part[HEADS][CH];
    __shared__ int jself_s;

    int tid = threadIdx.x, wave = tid >> 6, lane = tid & 63;
    int gid = blockIdx.x * NT + tid;

    // ---- P1: edges into N-1; claim S1 (pos: 0=no, 1=transient, u+2=member) --
    for (int e = gid; e < E; e += NB * NT) {
        int d = ei[E + e];
        if (d == N - 1) {
            int s = ei[e];
            int j = atomicAdd(&cnt[0], 1);
            if (j < CAP_E2) e2_src[j] = s;
            if (atomicCAS(&pos[s], 0, 1) == 0) {
                int u = atomicAdd(&cnt[1], 1);
                if (u < CAP_U) { uniq[u] = s; pos[s] = u + 2; } else pos[s] = 2;
            }
        }
    }
    if (gid == 0) {  // appended self loop of node N-1
        int j = atomicAdd(&cnt[0], 1);
        if (j < CAP_E2) e2_src[j] = N - 1;
        if (atomicCAS(&pos[N - 1], 0, 1) == 0) {
            int u = atomicAdd(&cnt[1], 1);
            if (u < CAP_U) { uniq[u] = N - 1; pos[N - 1] = u + 2; } else pos[N - 1] = 2;
        }
    }
    gbar(bar);

    // ---- P2: collect edges with dst in S1; self h0 rows per S1 node --------
    int ucnt = min(cnt[1], CAP_U);
    for (int e = gid; e < E; e += NB * NT) {
        int d = ei[E + e];
        if (pos[d] >= 2) {
            int j = atomicAdd(&cnt[2], 1);
            if (j < H0CAP) { e1s[j] = ei[e]; e1d[j] = d; }
        }
    }
    for (int u = blockIdx.x; u < ucnt; u += NB) {
        int node = uniq[u];
        if (tid < CH) xr[tid] = emb[(long)y[node] * CH + tid];
        __syncthreads();
        float acc = 0.f;
        #pragma unroll
        for (int k = 0; k < CH; ++k) acc = fmaf(xr[k], W0[k * HC + tid], acc);
        h0self[(long)u * HC + tid] = acc;
        float rs = wave_sum64(acc * as0[tid]);
        if (lane == 0) alss[u * HEADS + wave] = rs;
        float rd = wave_sum64(acc * ad0[tid]);
        if (lane == 0) alds[u * HEADS + wave] = rd;
        __syncthreads();
    }
    gbar(bar);

    // ---- P3: h0 row + a_src logit per layer-0 edge --------------------------
    int ce1 = min(cnt[2], H0CAP);
    for (int i = blockIdx.x; i < ce1; i += NB) {
        int node = e1s[i];
        if (tid < CH) xr[tid] = emb[(long)y[node] * CH + tid];
        __syncthreads();
        float acc = 0.f;
        #pragma unroll
        for (int k = 0; k < CH; ++k) acc = fmaf(xr[k], W0[k * HC + tid], acc);
        h0[(long)i * HC + tid] = acc;
        float r = wave_sum64(acc * as0[tid]);
        if (lane == 0) als0[i * HEADS + wave] = r;
        __syncthreads();
    }
    gbar(bar);

    // ---- P4: per S1 node attention/aggregate/elu/norm + fused layer-1 GEMV --
    int ne = min(cnt[0], CAP_E2);
    for (int u = blockIdx.x; u < ucnt; u += NB) {
        int d = uniq[u];
        if (tid == 0) nloc_s = 0;
        __syncthreads();
        for (int i = tid; i < ce1; i += NT)
            if (e1d[i] == d) {
                int s = atomicAdd(&nloc_s, 1);
                if (s < MAXD) gidx[s] = i;
            }
        __syncthreads();
        int nloc = min(nloc_s, MAXD);
        for (int idx = tid; idx < (nloc + 1) * HEADS; idx += NT) {
            int j = idx >> 2, h = idx & 3;
            float asv = (j < nloc) ? als0[gidx[j] * HEADS + h] : alss[u * HEADS + h];
            float e = asv + alds[u * HEADS + h];
            earr[j][h] = (e >= 0.f) ? e : NEG * e;
        }
        __syncthreads();
        if (tid < HEADS) {
            float m = -1e30f;
            for (int j = 0; j <= nloc; ++j) m = fmaxf(m, earr[j][tid]);
            float den = 0.f;
            for (int j = 0; j <= nloc; ++j) { float w = expf(earr[j][tid] - m); earr[j][tid] = w; den += w; }
            float inv = 1.f / (den + 1e-16f);
            for (int j = 0; j <= nloc; ++j) earr[j][tid] *= inv;
        }
        __syncthreads();
        float acc = 0.f;
        for (int j = 0; j < nloc; ++j)
            acc = fmaf(earr[j][wave], h0[(long)gidx[j] * HC + tid], acc);
        acc = fmaf(earr[nloc][wave], h0self[(long)u * HC + tid], acc);
        float o = acc + b0[tid];
        o = (o > 0.f) ? o : expm1f(o);
        float ss = wave_sum64(o * o);
        if (lane == 0) red[wave] = ss;
        __syncthreads();
        float nrm = sqrtf(red[0] + red[1] + red[2] + red[3]);
        xr[tid] = o / fmaxf(nrm, 1e-12f);  // x1 of node d in LDS
        __syncthreads();
        // fused layer-1 rows for e2 edges sourced at this node
        for (int j = 0; j < ne; ++j) {
            if (pos[e2_src[j]] - 2 != u) continue;  // wave-uniform
            float a1 = 0.f;
            #pragma unroll 16
            for (int k = 0; k < HC; ++k) a1 = fmaf(xr[k], W1[k * HC + tid], a1);
            h1[j * HC + tid] = a1;
            float r = wave_sum64(a1 * as1[tid]);
            if (lane == 0) als1[j * HEADS + wave] = r;
        }
        __syncthreads();
    }
    gbar(bar);

    // ---- P5: attention at N-1 + ctx MLP (block 0 only) ----------------------
    if (blockIdx.x == 0) {
        if (tid == 0) {
            jself_s = 0;
            for (int j = 0; j < ne; ++j) if (e2_src[j] == N - 1) { jself_s = j; break; }
        }
        __syncthreads();
        int jself = jself_s;
        {
            float r = wave_sum64(h1[jself * HC + tid] * ad1[tid]);
            if (lane == 0) red[wave] = r;  // reuse red as al_dst
        }
        __syncthreads();
        for (int idx = tid; idx < ne * HEADS; idx += NT) {
            int j = idx >> 2, h = idx & 3;
            float e = als1[j * HEADS + h] + red[h];
            earr[j][h] = (e >= 0.f) ? e : NEG * e;
        }
        __syncthreads();
        if (tid < HEADS) {
            float m = -1e30f;
            for (int j = 0; j < ne; ++j) m = fmaxf(m, earr[j][tid]);
            float den = 0.f;
            for (int j = 0; j < ne; ++j) { float w = expf(earr[j][tid] - m); earr[j][tid] = w; den += w; }
            float inv = 1.f / (den + 1e-16f);
            for (int j = 0; j < ne; ++j) earr[j][tid] *= inv;
        }
        __syncthreads();
        float acc = 0.f;
        for (int j = 0; j < ne; ++j)
            acc = fmaf(earr[j][wave], h1[j * HC + tid], acc);
        float o = acc + b1[tid];
        o = (o > 0.f) ? o : expm1f(o);
        float ss = wave_sum64(o * o);
        __syncthreads();   // red still holds al_dst; safe to overwrite after sync
        if (lane == 0) red[wave] = ss;
        __syncthreads();
        float nrm = sqrtf(red[0] + red[1] + red[2] + red[3]);
        xr[tid] = o / fmaxf(nrm, 1e-12f);  // ctx in LDS
        __syncthreads();
        int col = tid & 63;
        float hv = 0.f;
        #pragma unroll 16
        for (int k = wave * 64; k < wave * 64 + 64; ++k)
            hv = fmaf(xr[k], pw1[k * CH + col], hv);
        part[wave][col] = hv;
        __syncthreads();
        if (tid < CH) {
            float v = part[0][tid] + part[1][tid] + part[2][tid] + part[3][tid] + pb1[tid];
            hidden[tid] = fmaxf(v, 0.f);
        }
    }
    gbar(bar);

    // ---- P6: out = hidden @ pw2 + pb2 (grid-stride) --------------------------
    if (tid < CH) xr[tid] = hidden[tid];
    __syncthreads();
    int V4 = V >> 2;
    for (int q = gid; q < V4; q += NB * NT) {
        int v0 = q * 4;
        float4 acc = *(const float4*)(pb2 + v0);
        #pragma unroll 8
        for (int k = 0; k < CH; ++k) {
            float hk = xr[k];
            float4 w = *(const float4*)(pw2 + (size_t)k * V + v0);
            acc.x = fmaf(hk, w.x, acc.x);
            acc.y = fmaf(hk, w.y, acc.y);
            acc.z = fmaf(hk, w.z, acc.z);
            acc.w = fmaf(hk, w.w, acc.w);
        }
        *(float4*)(out + v0) = acc;
    }
    for (int v = (V4 << 2) + gid; v < V; v += NB * NT) {  // tail (V%4)
        float acc = pb2[v];
        for (int k = 0; k < CH; ++k) acc = fmaf(xr[k], pw2[(size_t)k * V + v], acc);
        out[v] = acc;
    }
}

extern "C" void kernel_launch(void* const* d_in, const int* in_sizes, int n_in,
                              void* d_out, int out_size, void* d_ws, size_t ws_size,
                              hipStream_t stream) {
    const int*   y      = (const int*)d_in[0];
    const int*   ei     = (const int*)d_in[1];
    const float* emb    = (const float*)d_in[2];
    const float* W0     = (const float*)d_in[3];
    const float* a_src0 = (const float*)d_in[4];
    const float* a_dst0 = (const float*)d_in[5];
    const float* b0     = (const float*)d_in[6];
    const float* W1     = (const float*)d_in[7];
    const float* a_src1 = (const float*)d_in[8];
    const float* a_dst1 = (const float*)d_in[9];
    const float* b1     = (const float*)d_in[10];
    const float* pw1    = (const float*)d_in[11];
    const float* pb1    = (const float*)d_in[12];
    const float* pw2    = (const float*)d_in[13];
    const float* pb2    = (const float*)d_in[14];
    int N = in_sizes[0];
    int E = in_sizes[1] / 2;
    int V = in_sizes[14];
    float* out = (float*)d_out;

    char* p = (char*)d_ws;
    auto alloc = [&](size_t bytes) {
        char* r = p;
        p += (bytes + 255) & ~(size_t)255;
        return r;
    };
    // zeroed region: bar[2] @0, cnt[3] @4, pos[N] @16
    int*   ints    = (int*)alloc((size_t)(16 + N) * sizeof(int));
    int*   bar     = ints;
    int*   cnt     = ints + 4;
    int*   pos     = ints + 16;
    float* hidden  = (float*)alloc(CH * sizeof(float));
    int*   e2      = (int*)alloc(CAP_E2 * sizeof(int));
    int*   uniq    = (int*)alloc(CAP_U * sizeof(int));
    int*   e1s     = (int*)alloc(H0CAP * sizeof(int));
    int*   e1d     = (int*)alloc(H0CAP * sizeof(int));
    float* als0    = (float*)alloc((size_t)H0CAP * HEADS * sizeof(float));
    float* alss    = (float*)alloc((size_t)CAP_U * HEADS * sizeof(float));
    float* alds    = (float*)alloc((size_t)CAP_U * HEADS * sizeof(float));
    float* als1    = (float*)alloc((size_t)CAP_E2 * HEADS * sizeof(float));
    float* h0      = (float*)alloc((size_t)H0CAP * HC * sizeof(float));
    float* h0self  = (float*)alloc((size_t)CAP_U * HC * sizeof(float));
    float* h1      = (float*)alloc((size_t)CAP_E2 * HC * sizeof(float));

    hipMemsetAsync(ints, 0, (size_t)(16 + N) * sizeof(int), stream);

    k_mega<<<NB, NT, 0, stream>>>(y, ei, emb, W0, a_src0, a_dst0, b0,
                                  W1, a_src1, a_dst1, b1, pw1, pb1, pw2, pb2,
                                  bar, cnt, pos, e2, uniq, e1s, e1d,
                                  als0, alss, alds, als1, h0, h0self, h1,
                                  hidden, out, N, E, V);
}

// Round 6
// 176.977 us; speedup vs baseline: 2.6875x; 1.3426x over previous
//
#include <hip/hip_runtime.h>
#include <math.h>

#define HEADS 4
#define CH 64
#define HC 256
#define NEG 0.2f

#define NB 256   // grid blocks, 1/CU: co-residency by capacity (4KB LDS, ~64 VGPR)
#define NT 256

// caps (expected: deg(N-1)~17, |S1|~18, e1~320)
#define CAP_E2 64
#define CAP_U  512
#define H0CAP  4096
#define MAXD   64
#define LCAP   64   // per-block discovered-edge list (expected ~1.2, Poisson tail << 64)

#define AG __HIP_MEMORY_SCOPE_AGENT

__device__ __forceinline__ float wave_sum64(float v) {
    #pragma unroll
    for (int off = 32; off; off >>= 1) v += __shfl_down(v, off, 64);
    return v;  // valid in lane 0
}

// write-through publish: global_store with sc0+sc1 -> visible at IF, no dirty L2
__device__ __forceinline__ void pubi(int* p, int v) {
    __hip_atomic_store(p, v, __ATOMIC_RELAXED, AG);
}
__device__ __forceinline__ void pubf(float* p, float v) {
    __hip_atomic_store(p, v, __ATOMIC_RELAXED, AG);
}

// fence-free grid barrier: publishes are write-through (already at IF once
// vmcnt drains, which __syncthreads guarantees), so no wbl2/inv needed.
// bar[0]=arrive count, bar[1]=generation; last arriver writes both as one
// 64-bit store {0, gen+1}.
__device__ __forceinline__ void gbar(int* bar) {
    __syncthreads();
    if (threadIdx.x == 0) {
        int g = __hip_atomic_load(&bar[1], __ATOMIC_RELAXED, AG);
        int a = __hip_atomic_fetch_add(&bar[0], 1, __ATOMIC_RELAXED, AG) + 1;
        if (a == NB) {
            unsigned long long packed = ((unsigned long long)(unsigned)(g + 1)) << 32;
            __hip_atomic_store((unsigned long long*)bar, packed, __ATOMIC_RELAXED, AG);
        } else {
            while (__hip_atomic_load(&bar[1], __ATOMIC_RELAXED, AG) == g)
                __builtin_amdgcn_s_sleep(2);
        }
    }
    __syncthreads();
}

__global__ __launch_bounds__(NT) void k_mega(
    const int* __restrict__ y, const int* __restrict__ ei,
    const float* __restrict__ emb,
    const float* __restrict__ W0, const float* __restrict__ as0,
    const float* __restrict__ ad0, const float* __restrict__ b0,
    const float* __restrict__ W1, const float* __restrict__ as1,
    const float* __restrict__ ad1, const float* __restrict__ b1,
    const float* __restrict__ pw1, const float* __restrict__ pb1,
    const float* __restrict__ pw2, const float* __restrict__ pb2,
    int* __restrict__ bar, int* __restrict__ cnt, int* __restrict__ pos,
    int* __restrict__ e2_src, int* __restrict__ uniq,
    int* __restrict__ e1d,
    float* __restrict__ als0, float* __restrict__ alss,
    float* __restrict__ alds, float* __restrict__ als1,
    float* __restrict__ h0, float* __restrict__ h0self,
    float* __restrict__ h1,
    float* __restrict__ out, int N, int E, int V)
{
    __shared__ float xr[HC];
    __shared__ int list_n;
    __shared__ int list_a[LCAP], list_b[LCAP];
    __shared__ int gidx[MAXD];
    __shared__ int nloc_s, jself_s;
    __shared__ float earr[MAXD + 1][HEADS];
    __shared__ float red[HEADS];
    __shared__ float part[HEADS][CH];
    __shared__ float hsh[CH];

    int tid = threadIdx.x, wave = tid >> 6, lane = tid & 63;
    int gid = blockIdx.x * NT + tid;

    // ======== P1: scan for dst==N-1; claim S1; compute self h0 rows ========
    if (tid == 0) list_n = 0;
    __syncthreads();
    for (int e = gid; e < E; e += NB * NT) {
        if (ei[E + e] == N - 1) {
            int s = ei[e];
            int j = atomicAdd(&cnt[0], 1);
            if (j < CAP_E2) pubi(&e2_src[j], s);
            if (atomicCAS(&pos[s], 0, 1) == 0) {
                int u = atomicAdd(&cnt[1], 1);
                if (u < CAP_U) {
                    pubi(&uniq[u], s);
                    pubi(&pos[s], u + 2);
                    int t = atomicAdd(&list_n, 1);
                    if (t < LCAP) { list_a[t] = u; list_b[t] = s; }
                } else pubi(&pos[s], 2);
            }
        }
    }
    if (gid == 0) {  // appended self loop of node N-1
        int j = atomicAdd(&cnt[0], 1);
        if (j < CAP_E2) pubi(&e2_src[j], N - 1);
        if (atomicCAS(&pos[N - 1], 0, 1) == 0) {
            int u = atomicAdd(&cnt[1], 1);
            if (u < CAP_U) {
                pubi(&uniq[u], N - 1);
                pubi(&pos[N - 1], u + 2);
                int t = atomicAdd(&list_n, 1);
                if (t < LCAP) { list_a[t] = u; list_b[t] = N - 1; }
            } else pubi(&pos[N - 1], 2);
        }
    }
    __syncthreads();
    int ln = min(list_n, LCAP);
    for (int t = 0; t < ln; ++t) {
        int u = list_a[t], node = list_b[t];
        if (tid < CH) xr[tid] = emb[(long)y[node] * CH + tid];
        __syncthreads();
        float acc = 0.f;
        #pragma unroll
        for (int k = 0; k < CH; ++k) acc = fmaf(xr[k], W0[k * HC + tid], acc);
        pubf(&h0self[(long)u * HC + tid], acc);
        float rs = wave_sum64(acc * as0[tid]);
        if (lane == 0) pubf(&alss[u * HEADS + wave], rs);
        float rd = wave_sum64(acc * ad0[tid]);
        if (lane == 0) pubf(&alds[u * HEADS + wave], rd);
        __syncthreads();
    }
    gbar(bar);

    // ======== P2: scan for dst in S1; compute h0 edge rows in-block ========
    if (tid == 0) list_n = 0;
    __syncthreads();
    for (int e = gid; e < E; e += NB * NT) {
        int d = ei[E + e];
        if (pos[d] >= 2) {                       // plain read, pos final
            int j = atomicAdd(&cnt[2], 1);
            if (j < H0CAP) {
                pubi(&e1d[j], d);
                int t = atomicAdd(&list_n, 1);
                if (t < LCAP) { list_a[t] = j; list_b[t] = ei[e]; }
            }
        }
    }
    __syncthreads();
    ln = min(list_n, LCAP);
    for (int t = 0; t < ln; ++t) {
        int j = list_a[t], node = list_b[t];
        if (tid < CH) xr[tid] = emb[(long)y[node] * CH + tid];
        __syncthreads();
        float acc = 0.f;
        #pragma unroll
        for (int k = 0; k < CH; ++k) acc = fmaf(xr[k], W0[k * HC + tid], acc);
        pubf(&h0[(long)j * HC + tid], acc);
        float r = wave_sum64(acc * as0[tid]);
        if (lane == 0) pubf(&als0[j * HEADS + wave], r);
        __syncthreads();
    }
    gbar(bar);

    // ======== P3: per S1 node agg/softmax/elu/norm + fused h1 rows ========
    int ucnt = min(cnt[1], CAP_U);   // plain reads: counts final, first touch
    int ce1  = min(cnt[2], H0CAP);
    int ne   = min(cnt[0], CAP_E2);
    for (int u = blockIdx.x; u < ucnt; u += NB) {
        int d = uniq[u];
        if (tid == 0) nloc_s = 0;
        __syncthreads();
        for (int i = tid; i < ce1; i += NT)
            if (e1d[i] == d) {
                int s = atomicAdd(&nloc_s, 1);
                if (s < MAXD) gidx[s] = i;
            }
        __syncthreads();
        int nloc = min(nloc_s, MAXD);
        for (int idx = tid; idx < (nloc + 1) * HEADS; idx += NT) {
            int j = idx >> 2, h = idx & 3;
            float asv = (j < nloc) ? als0[gidx[j] * HEADS + h] : alss[u * HEADS + h];
            float e = asv + alds[u * HEADS + h];
            earr[j][h] = (e >= 0.f) ? e : NEG * e;
        }
        __syncthreads();
        if (tid < HEADS) {
            float m = -1e30f;
            for (int j = 0; j <= nloc; ++j) m = fmaxf(m, earr[j][tid]);
            float den = 0.f;
            for (int j = 0; j <= nloc; ++j) { float w = expf(earr[j][tid] - m); earr[j][tid] = w; den += w; }
            float inv = 1.f / (den + 1e-16f);
            for (int j = 0; j <= nloc; ++j) earr[j][tid] *= inv;
        }
        __syncthreads();
        float acc = 0.f;
        for (int j = 0; j < nloc; ++j)
            acc = fmaf(earr[j][wave], h0[(long)gidx[j] * HC + tid], acc);
        acc = fmaf(earr[nloc][wave], h0self[(long)u * HC + tid], acc);
        float o = acc + b0[tid];
        o = (o > 0.f) ? o : expm1f(o);
        float ss = wave_sum64(o * o);
        if (lane == 0) red[wave] = ss;
        __syncthreads();
        float nrm = sqrtf(red[0] + red[1] + red[2] + red[3]);
        xr[tid] = o / fmaxf(nrm, 1e-12f);     // x1 of node d
        __syncthreads();
        for (int j = 0; j < ne; ++j) {
            if (pos[e2_src[j]] - 2 != u) continue;  // wave-uniform
            float a1 = 0.f;
            #pragma unroll 16
            for (int k = 0; k < HC; ++k) a1 = fmaf(xr[k], W1[k * HC + tid], a1);
            pubf(&h1[j * HC + tid], a1);
            float r = wave_sum64(a1 * as1[tid]);
            if (lane == 0) pubf(&als1[j * HEADS + wave], r);
        }
        __syncthreads();
    }
    gbar(bar);

    // ======== P4: final attention + pw1 MLP (redundant per block), out GEMV ==
    if (tid == 0) {
        jself_s = 0;
        for (int j = 0; j < ne; ++j) if (e2_src[j] == N - 1) { jself_s = j; break; }
    }
    __syncthreads();
    int jself = jself_s;
    {
        float r = wave_sum64(h1[jself * HC + tid] * ad1[tid]);
        if (lane == 0) red[wave] = r;  // al_dst
    }
    __syncthreads();
    for (int idx = tid; idx < ne * HEADS; idx += NT) {
        int j = idx >> 2, h = idx & 3;
        float e = als1[j * HEADS + h] + red[h];
        earr[j][h] = (e >= 0.f) ? e : NEG * e;
    }
    __syncthreads();
    if (tid < HEADS) {
        float m = -1e30f;
        for (int j = 0; j < ne; ++j) m = fmaxf(m, earr[j][tid]);
        float den = 0.f;
        for (int j = 0; j < ne; ++j) { float w = expf(earr[j][tid] - m); earr[j][tid] = w; den += w; }
        float inv = 1.f / (den + 1e-16f);
        for (int j = 0; j < ne; ++j) earr[j][tid] *= inv;
    }
    __syncthreads();
    float acc = 0.f;
    for (int j = 0; j < ne; ++j)
        acc = fmaf(earr[j][wave], h1[j * HC + tid], acc);
    float o = acc + b1[tid];
    o = (o > 0.f) ? o : expm1f(o);
    float ss = wave_sum64(o * o);
    __syncthreads();   // red read above is done
    if (lane == 0) red[wave] = ss;
    __syncthreads();
    float nrm = sqrtf(red[0] + red[1] + red[2] + red[3]);
    xr[tid] = o / fmaxf(nrm, 1e-12f);  // ctx
    __syncthreads();
    {
        int col = tid & 63;
        float hv = 0.f;
        #pragma unroll 16
        for (int k = wave * 64; k < wave * 64 + 64; ++k)
            hv = fmaf(xr[k], pw1[k * CH + col], hv);
        part[wave][col] = hv;
    }
    __syncthreads();
    if (tid < CH) {
        float v = part[0][tid] + part[1][tid] + part[2][tid] + part[3][tid] + pb1[tid];
        hsh[tid] = fmaxf(v, 0.f);
    }
    __syncthreads();

    int V4 = V >> 2;
    for (int q = gid; q < V4; q += NB * NT) {
        int v0 = q * 4;
        float4 a4 = *(const float4*)(pb2 + v0);
        #pragma unroll 8
        for (int k = 0; k < CH; ++k) {
            float hk = hsh[k];
            float4 w = *(const float4*)(pw2 + (size_t)k * V + v0);
            a4.x = fmaf(hk, w.x, a4.x);
            a4.y = fmaf(hk, w.y, a4.y);
            a4.z = fmaf(hk, w.z, a4.z);
            a4.w = fmaf(hk, w.w, a4.w);
        }
        *(float4*)(out + v0) = a4;
    }
    for (int v = (V4 << 2) + gid; v < V; v += NB * NT) {
        float a1 = pb2[v];
        for (int k = 0; k < CH; ++k) a1 = fmaf(hsh[k], pw2[(size_t)k * V + v], a1);
        out[v] = a1;
    }
}

extern "C" void kernel_launch(void* const* d_in, const int* in_sizes, int n_in,
                              void* d_out, int out_size, void* d_ws, size_t ws_size,
                              hipStream_t stream) {
    const int*   y      = (const int*)d_in[0];
    const int*   ei     = (const int*)d_in[1];
    const float* emb    = (const float*)d_in[2];
    const float* W0     = (const float*)d_in[3];
    const float* a_src0 = (const float*)d_in[4];
    const float* a_dst0 = (const float*)d_in[5];
    const float* b0     = (const float*)d_in[6];
    const float* W1     = (const float*)d_in[7];
    const float* a_src1 = (const float*)d_in[8];
    const float* a_dst1 = (const float*)d_in[9];
    const float* b1     = (const float*)d_in[10];
    const float* pw1    = (const float*)d_in[11];
    const float* pb1    = (const float*)d_in[12];
    const float* pw2    = (const float*)d_in[13];
    const float* pb2    = (const float*)d_in[14];
    int N = in_sizes[0];
    int E = in_sizes[1] / 2;
    int V = in_sizes[14];
    float* out = (float*)d_out;

    char* p = (char*)d_ws;
    auto alloc = [&](size_t bytes) {
        char* r = p;
        p += (bytes + 255) & ~(size_t)255;
        return r;
    };
    // zeroed region: bar @0 (own cacheline), cnt @16 ints, pos @32 ints
    int*   ints    = (int*)alloc((size_t)(32 + N) * sizeof(int));
    int*   bar     = ints;
    int*   cnt     = ints + 16;
    int*   pos     = ints + 32;
    int*   e2      = (int*)alloc(CAP_E2 * sizeof(int));
    int*   uniq    = (int*)alloc(CAP_U * sizeof(int));
    int*   e1d     = (int*)alloc(H0CAP * sizeof(int));
    float* als0    = (float*)alloc((size_t)H0CAP * HEADS * sizeof(float));
    float* alss    = (float*)alloc((size_t)CAP_U * HEADS * sizeof(float));
    float* alds    = (float*)alloc((size_t)CAP_U * HEADS * sizeof(float));
    float* als1    = (float*)alloc((size_t)CAP_E2 * HEADS * sizeof(float));
    float* h0      = (float*)alloc((size_t)H0CAP * HC * sizeof(float));
    float* h0self  = (float*)alloc((size_t)CAP_U * HC * sizeof(float));
    float* h1      = (float*)alloc((size_t)CAP_E2 * HC * sizeof(float));

    hipMemsetAsync(ints, 0, (size_t)(32 + N) * sizeof(int), stream);

    k_mega<<<NB, NT, 0, stream>>>(y, ei, emb, W0, a_src0, a_dst0, b0,
                                  W1, a_src1, a_dst1, b1, pw1, pb1, pw2, pb2,
                                  bar, cnt, pos, e2, uniq, e1d,
                                  als0, alss, alds, als1, h0, h0self, h1,
                                  out, N, E, V);
}

// Round 7
// 154.004 us; speedup vs baseline: 3.0884x; 1.1492x over previous
//
#include <hip/hip_runtime.h>
#include <math.h>

#define HEADS 4
#define CH 64
#define HC 256
#define NEG 0.2f

#define NB 256   // grid blocks, 1/CU
#define NT 256
#define NGRP 16  // barrier tree groups (16 blocks/group)

// caps (expected: deg(N-1)~17, |S1|~18, e1~320)
#define CAP_E2 64
#define CAP_U  512
#define H0CAP  4096
#define MAXD   64
#define LCAP   64

#define AG __HIP_MEMORY_SCOPE_AGENT

__device__ __forceinline__ float wave_sum64(float v) {
    #pragma unroll
    for (int off = 32; off; off >>= 1) v += __shfl_down(v, off, 64);
    return v;  // valid in lane 0
}

// write-through publish (sc0+sc1 store -> visible at IF; no dirty L2 lines)
__device__ __forceinline__ void pubi(int* p, int v) {
    __hip_atomic_store(p, v, __ATOMIC_RELAXED, AG);
}
__device__ __forceinline__ void pubf(float* p, float v) {
    __hip_atomic_store(p, v, __ATOMIC_RELAXED, AG);
}

// two-level monotonic grid barrier. Layout (ints): gen@0, root@32,
// group g counter @ 64+g*32 (one 128B line each). Counters never reset:
// barrier #phase completes when group hits phase*(NB/NGRP) and root hits
// phase*NGRP. No reset -> no relaxed-ordering race. Contention per line:
// NB/NGRP=16 ops instead of 256.
__device__ __forceinline__ void gbar(int* bar, int phase) {
    __syncthreads();
    if (threadIdx.x == 0) {
        int g = blockIdx.x & (NGRP - 1);
        int a = __hip_atomic_fetch_add(&bar[64 + g * 32], 1, __ATOMIC_RELAXED, AG) + 1;
        if (a == phase * (NB / NGRP)) {
            int r = __hip_atomic_fetch_add(&bar[32], 1, __ATOMIC_RELAXED, AG) + 1;
            if (r == phase * NGRP)
                __hip_atomic_store(&bar[0], phase, __ATOMIC_RELAXED, AG);
        }
        while (__hip_atomic_load(&bar[0], __ATOMIC_RELAXED, AG) < phase)
            __builtin_amdgcn_s_sleep(1);
    }
    __syncthreads();
}

__global__ __launch_bounds__(NT) void k_mega(
    const int* __restrict__ y, const int* __restrict__ ei,
    const float* __restrict__ emb,
    const float* __restrict__ W0, const float* __restrict__ as0,
    const float* __restrict__ ad0, const float* __restrict__ b0,
    const float* __restrict__ W1, const float* __restrict__ as1,
    const float* __restrict__ ad1, const float* __restrict__ b1,
    const float* __restrict__ pw1, const float* __restrict__ pb1,
    const float* __restrict__ pw2, const float* __restrict__ pb2,
    int* __restrict__ bar, int* __restrict__ cnt, int* __restrict__ pos,
    int* __restrict__ e2_src, int* __restrict__ uniq,
    int* __restrict__ e1d,
    float* __restrict__ als0, float* __restrict__ alss,
    float* __restrict__ alds, float* __restrict__ als1,
    float* __restrict__ h0, float* __restrict__ h0self,
    float* __restrict__ h1,
    float* __restrict__ out, int N, int E, int V)
{
    __shared__ float xr[HC];
    __shared__ int list_n;
    __shared__ int list_a[LCAP], list_b[LCAP];
    __shared__ int gidx[MAXD];
    __shared__ int nloc_s, jself_s;
    __shared__ float earr[MAXD + 1][HEADS];
    __shared__ float red[HEADS];
    __shared__ float part[HEADS][CH];
    __shared__ float hsh[CH];

    int tid = threadIdx.x, wave = tid >> 6, lane = tid & 63;
    int gid = blockIdx.x * NT + tid;
    const int stride = NB * NT;
    const int NL = N - 1;

    // ======== P1: scan dst==N-1 (unroll x4); claim S1; self h0 rows ========
    if (tid == 0) list_n = 0;
    __syncthreads();
    {
        auto handle = [&](int e) {
            int s = ei[e];
            int j = atomicAdd(&cnt[0], 1);
            if (j < CAP_E2) pubi(&e2_src[j], s);
            if (atomicCAS(&pos[s], 0, 1) == 0) {
                int u = atomicAdd(&cnt[1], 1);
                if (u < CAP_U) {
                    pubi(&uniq[u], s);
                    pubi(&pos[s], u + 2);
                    int t = atomicAdd(&list_n, 1);
                    if (t < LCAP) { list_a[t] = u; list_b[t] = s; }
                } else pubi(&pos[s], 2);
            }
        };
        int e = gid;
        for (; e + 3 * stride < E; e += 4 * stride) {
            int d0 = ei[E + e], d1 = ei[E + e + stride];
            int d2 = ei[E + e + 2 * stride], d3 = ei[E + e + 3 * stride];
            if (d0 == NL) handle(e);
            if (d1 == NL) handle(e + stride);
            if (d2 == NL) handle(e + 2 * stride);
            if (d3 == NL) handle(e + 3 * stride);
        }
        for (; e < E; e += stride)
            if (ei[E + e] == NL) handle(e);
    }
    if (gid == 0) {  // appended self loop of node N-1
        int j = atomicAdd(&cnt[0], 1);
        if (j < CAP_E2) pubi(&e2_src[j], NL);
        if (atomicCAS(&pos[NL], 0, 1) == 0) {
            int u = atomicAdd(&cnt[1], 1);
            if (u < CAP_U) {
                pubi(&uniq[u], NL);
                pubi(&pos[NL], u + 2);
                int t = atomicAdd(&list_n, 1);
                if (t < LCAP) { list_a[t] = u; list_b[t] = NL; }
            } else pubi(&pos[NL], 2);
        }
    }
    __syncthreads();
    int ln = min(list_n, LCAP);
    for (int t = 0; t < ln; ++t) {
        int u = list_a[t], node = list_b[t];
        if (tid < CH) xr[tid] = emb[(long)y[node] * CH + tid];
        __syncthreads();
        float acc = 0.f;
        #pragma unroll
        for (int k = 0; k < CH; ++k) acc = fmaf(xr[k], W0[k * HC + tid], acc);
        pubf(&h0self[(long)u * HC + tid], acc);
        float rs = wave_sum64(acc * as0[tid]);
        if (lane == 0) pubf(&alss[u * HEADS + wave], rs);
        float rd = wave_sum64(acc * ad0[tid]);
        if (lane == 0) pubf(&alds[u * HEADS + wave], rd);
        __syncthreads();
    }
    gbar(bar, 1);

    // ======== P2: scan dst in S1 (unroll x4, batched pos loads); h0 rows ====
    if (tid == 0) list_n = 0;
    __syncthreads();
    {
        auto handle = [&](int e, int d) {
            int j = atomicAdd(&cnt[2], 1);
            if (j < H0CAP) {
                pubi(&e1d[j], d);
                int t = atomicAdd(&list_n, 1);
                if (t < LCAP) { list_a[t] = j; list_b[t] = ei[e]; }
            }
        };
        int e = gid;
        for (; e + 3 * stride < E; e += 4 * stride) {
            int d0 = ei[E + e], d1 = ei[E + e + stride];
            int d2 = ei[E + e + 2 * stride], d3 = ei[E + e + 3 * stride];
            int p0 = pos[d0], p1 = pos[d1], p2 = pos[d2], p3 = pos[d3];
            if (p0 >= 2) handle(e, d0);
            if (p1 >= 2) handle(e + stride, d1);
            if (p2 >= 2) handle(e + 2 * stride, d2);
            if (p3 >= 2) handle(e + 3 * stride, d3);
        }
        for (; e < E; e += stride) {
            int d = ei[E + e];
            if (pos[d] >= 2) handle(e, d);
        }
    }
    __syncthreads();
    ln = min(list_n, LCAP);
    for (int t = 0; t < ln; ++t) {
        int j = list_a[t], node = list_b[t];
        if (tid < CH) xr[tid] = emb[(long)y[node] * CH + tid];
        __syncthreads();
        float acc = 0.f;
        #pragma unroll
        for (int k = 0; k < CH; ++k) acc = fmaf(xr[k], W0[k * HC + tid], acc);
        pubf(&h0[(long)j * HC + tid], acc);
        float r = wave_sum64(acc * as0[tid]);
        if (lane == 0) pubf(&als0[j * HEADS + wave], r);
        __syncthreads();
    }
    gbar(bar, 2);

    // ======== P3: per S1 node agg/softmax/elu/norm + fused h1 rows ========
    int ucnt = min(cnt[1], CAP_U);
    int ce1  = min(cnt[2], H0CAP);
    int ne   = min(cnt[0], CAP_E2);
    for (int u = blockIdx.x; u < ucnt; u += NB) {
        int d = uniq[u];
        if (tid == 0) nloc_s = 0;
        __syncthreads();
        for (int i = tid; i < ce1; i += NT)
            if (e1d[i] == d) {
                int s = atomicAdd(&nloc_s, 1);
                if (s < MAXD) gidx[s] = i;
            }
        __syncthreads();
        int nloc = min(nloc_s, MAXD);
        for (int idx = tid; idx < (nloc + 1) * HEADS; idx += NT) {
            int j = idx >> 2, h = idx & 3;
            float asv = (j < nloc) ? als0[gidx[j] * HEADS + h] : alss[u * HEADS + h];
            float e = asv + alds[u * HEADS + h];
            earr[j][h] = (e >= 0.f) ? e : NEG * e;
        }
        __syncthreads();
        if (tid < HEADS) {
            float m = -1e30f;
            for (int j = 0; j <= nloc; ++j) m = fmaxf(m, earr[j][tid]);
            float den = 0.f;
            for (int j = 0; j <= nloc; ++j) { float w = expf(earr[j][tid] - m); earr[j][tid] = w; den += w; }
            float inv = 1.f / (den + 1e-16f);
            for (int j = 0; j <= nloc; ++j) earr[j][tid] *= inv;
        }
        __syncthreads();
        float acc = 0.f;
        for (int j = 0; j < nloc; ++j)
            acc = fmaf(earr[j][wave], h0[(long)gidx[j] * HC + tid], acc);
        acc = fmaf(earr[nloc][wave], h0self[(long)u * HC + tid], acc);
        float o = acc + b0[tid];
        o = (o > 0.f) ? o : expm1f(o);
        float ss = wave_sum64(o * o);
        if (lane == 0) red[wave] = ss;
        __syncthreads();
        float nrm = sqrtf(red[0] + red[1] + red[2] + red[3]);
        xr[tid] = o / fmaxf(nrm, 1e-12f);     // x1 of node d
        __syncthreads();
        for (int j = 0; j < ne; ++j) {
            if (pos[e2_src[j]] - 2 != u) continue;  // wave-uniform
            float a1 = 0.f;
            #pragma unroll 16
            for (int k = 0; k < HC; ++k) a1 = fmaf(xr[k], W1[k * HC + tid], a1);
            pubf(&h1[j * HC + tid], a1);
            float r = wave_sum64(a1 * as1[tid]);
            if (lane == 0) pubf(&als1[j * HEADS + wave], r);
        }
        __syncthreads();
    }
    gbar(bar, 3);

    // ======== P4: final attention + pw1 MLP (redundant per block), out GEMV ==
    if (tid == 0) {
        jself_s = 0;
        for (int j = 0; j < ne; ++j) if (e2_src[j] == NL) { jself_s = j; break; }
    }
    __syncthreads();
    int jself = jself_s;
    {
        float r = wave_sum64(h1[jself * HC + tid] * ad1[tid]);
        if (lane == 0) red[wave] = r;  // al_dst
    }
    __syncthreads();
    for (int idx = tid; idx < ne * HEADS; idx += NT) {
        int j = idx >> 2, h = idx & 3;
        float e = als1[j * HEADS + h] + red[h];
        earr[j][h] = (e >= 0.f) ? e : NEG * e;
    }
    __syncthreads();
    if (tid < HEADS) {
        float m = -1e30f;
        for (int j = 0; j < ne; ++j) m = fmaxf(m, earr[j][tid]);
        float den = 0.f;
        for (int j = 0; j < ne; ++j) { float w = expf(earr[j][tid] - m); earr[j][tid] = w; den += w; }
        float inv = 1.f / (den + 1e-16f);
        for (int j = 0; j < ne; ++j) earr[j][tid] *= inv;
    }
    __syncthreads();
    float acc = 0.f;
    for (int j = 0; j < ne; ++j)
        acc = fmaf(earr[j][wave], h1[j * HC + tid], acc);
    float o = acc + b1[tid];
    o = (o > 0.f) ? o : expm1f(o);
    float ss = wave_sum64(o * o);
    __syncthreads();
    if (lane == 0) red[wave] = ss;
    __syncthreads();
    float nrm = sqrtf(red[0] + red[1] + red[2] + red[3]);
    xr[tid] = o / fmaxf(nrm, 1e-12f);  // ctx
    __syncthreads();
    {
        int col = tid & 63;
        float hv = 0.f;
        #pragma unroll 16
        for (int k = wave * 64; k < wave * 64 + 64; ++k)
            hv = fmaf(xr[k], pw1[k * CH + col], hv);
        part[wave][col] = hv;
    }
    __syncthreads();
    if (tid < CH) {
        float v = part[0][tid] + part[1][tid] + part[2][tid] + part[3][tid] + pb1[tid];
        hsh[tid] = fmaxf(v, 0.f);
    }
    __syncthreads();

    int V4 = V >> 2;
    for (int q = gid; q < V4; q += NB * NT) {
        int v0 = q * 4;
        float4 a4 = *(const float4*)(pb2 + v0);
        #pragma unroll 8
        for (int k = 0; k < CH; ++k) {
            float hk = hsh[k];
            float4 w = *(const float4*)(pw2 + (size_t)k * V + v0);
            a4.x = fmaf(hk, w.x, a4.x);
            a4.y = fmaf(hk, w.y, a4.y);
            a4.z = fmaf(hk, w.z, a4.z);
            a4.w = fmaf(hk, w.w, a4.w);
        }
        *(float4*)(out + v0) = a4;
    }
    for (int v = (V4 << 2) + gid; v < V; v += NB * NT) {
        float a1 = pb2[v];
        for (int k = 0; k < CH; ++k) a1 = fmaf(hsh[k], pw2[(size_t)k * V + v], a1);
        out[v] = a1;
    }
}

extern "C" void kernel_launch(void* const* d_in, const int* in_sizes, int n_in,
                              void* d_out, int out_size, void* d_ws, size_t ws_size,
                              hipStream_t stream) {
    const int*   y      = (const int*)d_in[0];
    const int*   ei     = (const int*)d_in[1];
    const float* emb    = (const float*)d_in[2];
    const float* W0     = (const float*)d_in[3];
    const float* a_src0 = (const float*)d_in[4];
    const float* a_dst0 = (const float*)d_in[5];
    const float* b0     = (const float*)d_in[6];
    const float* W1     = (const float*)d_in[7];
    const float* a_src1 = (const float*)d_in[8];
    const float* a_dst1 = (const float*)d_in[9];
    const float* b1     = (const float*)d_in[10];
    const float* pw1    = (const float*)d_in[11];
    const float* pb1    = (const float*)d_in[12];
    const float* pw2    = (const float*)d_in[13];
    const float* pb2    = (const float*)d_in[14];
    int N = in_sizes[0];
    int E = in_sizes[1] / 2;
    int V = in_sizes[14];
    float* out = (float*)d_out;

    char* p = (char*)d_ws;
    auto alloc = [&](size_t bytes) {
        char* r = p;
        p += (bytes + 255) & ~(size_t)255;
        return r;
    };
    // zeroed region: barrier tree @0 (1024 ints), cnt @1024, pos @1056
    int*   ints    = (int*)alloc((size_t)(1056 + N) * sizeof(int));
    int*   bar     = ints;
    int*   cnt     = ints + 1024;
    int*   pos     = ints + 1056;
    int*   e2      = (int*)alloc(CAP_E2 * sizeof(int));
    int*   uniq    = (int*)alloc(CAP_U * sizeof(int));
    int*   e1d     = (int*)alloc(H0CAP * sizeof(int));
    float* als0    = (float*)alloc((size_t)H0CAP * HEADS * sizeof(float));
    float* alss    = (float*)alloc((size_t)CAP_U * HEADS * sizeof(float));
    float* alds    = (float*)alloc((size_t)CAP_U * HEADS * sizeof(float));
    float* als1    = (float*)alloc((size_t)CAP_E2 * HEADS * sizeof(float));
    float* h0      = (float*)alloc((size_t)H0CAP * HC * sizeof(float));
    float* h0self  = (float*)alloc((size_t)CAP_U * HC * sizeof(float));
    float* h1      = (float*)alloc((size_t)CAP_E2 * HC * sizeof(float));

    hipMemsetAsync(ints, 0, (size_t)(1056 + N) * sizeof(int), stream);

    k_mega<<<NB, NT, 0, stream>>>(y, ei, emb, W0, a_src0, a_dst0, b0,
                                  W1, a_src1, a_dst1, b1, pw1, pb1, pw2, pb2,
                                  bar, cnt, pos, e2, uniq, e1d,
                                  als0, alss, alds, als1, h0, h0self, h1,
                                  out, N, E, V);
}